// Round 1
// baseline (2065.582 us; speedup 1.0000x reference)
//
#include <hip/hip_runtime.h>
#include <math.h>

// Problem constants (fixed by the reference)
#define BB  4096
#define LL  168
#define AA  128
#define FNN 32

// One block per batch sample. 256 threads = 4 waves.
// Wave wid: p = wid>>1 selects row parity (rows l = 2r+p), h = wid&1 selects
// n-half [16h, 16h+16). Lane ln owns f = {2ln, 2ln+1}.
//
// v2 changes vs baseline (latency-stall-bound at 2.34 TB/s):
//  - depth-6 rotating prefetch of A rows (3 KB in flight per wave)
//  - conv_k staged in LDS once per block; per-row reads are wave-uniform
//    broadcast ds_read_b128 (no scalar-cache thrash, fine-grained lgkmcnt)
//  - stores balanced across all 4 waves (row-parity split within each p)
//  - wv kept in LDS across main loop (frees 16 VGPRs)
__global__ __launch_bounds__(256, 6)
void tpa_fused(const float* __restrict__ query,
               const float* __restrict__ attn_states,
               const float* __restrict__ W_q,
               const float* __restrict__ conv_k,
               const float* __restrict__ conv_b,
               const float* __restrict__ W_out,
               const float* __restrict__ b_out,
               float* __restrict__ out_attns,   // (B, A)
               float* __restrict__ out_states)  // (B, L-1, A)
{
    const int b    = blockIdx.x;
    const int t    = threadIdx.x;
    const int lane = t & 63;
    const int wid  = __builtin_amdgcn_readfirstlane(t >> 6);
    const int h    = wid & 1;    // n-half
    const int p    = wid >> 1;   // row parity

    __shared__ float sh_k[LL * FNN];   // 21504 B, conv_k staged per block
    __shared__ float qrow[256];
    __shared__ float red[512];
    __shared__ float sh_wv[32];
    __shared__ float sh_a[128];
    __shared__ float sh_dp[64];
    __shared__ float sh_d[32];

    // ---- stage query row + conv_k (5376 floats = 21 * 256) ----
    qrow[t] = query[(size_t)b * 256 + t];
    #pragma unroll
    for (int j = 0; j < 21; ++j)
        sh_k[j * 256 + t] = conv_k[j * 256 + t];
    __syncthreads();

    // ---- wv = qrow @ W_q (256x32), K-dim split over 8 chunks ----
    {
        const int n = t & 31, kc = t >> 5;
        float pp = 0.f;
        #pragma unroll
        for (int i = 0; i < 32; ++i) {
            const int k = (kc << 5) + i;
            pp += qrow[k] * W_q[k * FNN + n];
        }
        red[t] = pp;
    }
    __syncthreads();
    if (t < 32) {
        float s = 0.f;
        #pragma unroll
        for (int kc = 0; kc < 8; ++kc) s += red[(kc << 5) + t];
        sh_wv[t] = s;
    }
    __syncthreads();

    // ---- main stream: partial cv over this wave's row parity ----
    float cv0[16], cv1[16];
    #pragma unroll
    for (int n = 0; n < 16; ++n) { cv0[n] = 0.f; cv1[n] = 0.f; }

    const float* asp   = attn_states + (size_t)b * (LL * AA) + p * AA + lane * 2;
    float*       osp   = out_states  + (size_t)b * ((LL - 1) * AA) + lane * 2;
    const float* kbase = sh_k + h * 16;            // wave-uniform LDS base

    // depth-6 rotating prefetch over the 84 rows of this parity stream
    float2 ab[6];
    #pragma unroll
    for (int j = 0; j < 6; ++j)
        ab[j] = *(const float2*)(asp + (size_t)j * 256);

    for (int i = 0; i < 84; i += 6) {
        #pragma unroll
        for (int j = 0; j < 6; ++j) {
            const int r = i + j;                   // row index in parity stream
            const float2 av = ab[j];

            // prefetch row r+6 (clamped; tail re-loads row 83 harmlessly)
            int rp = r + 6; if (rp > 83) rp = 83;
            ab[j] = *(const float2*)(asp + (size_t)rp * 256);

            // shifted copy: rows split by (r&1) across the two h-waves
            if ((j & 1) == h) {                    // i is even -> (r&1)==(j&1)
                const int ro = 2 * r + p - 1;      // dest row
                if (ro >= 0)
                    *(float2*)(osp + (size_t)ro * AA) = av;
            }

            // k row from LDS: wave-uniform address -> broadcast, conflict-free
            const float* kp = kbase + (2 * r + p) * FNN;
            #pragma unroll
            for (int c = 0; c < 4; ++c) {
                const float4 kv = *(const float4*)(kp + c * 4);
                cv0[c * 4 + 0] += av.x * kv.x;
                cv0[c * 4 + 1] += av.x * kv.y;
                cv0[c * 4 + 2] += av.x * kv.z;
                cv0[c * 4 + 3] += av.x * kv.w;
                cv1[c * 4 + 0] += av.y * kv.x;
                cv1[c * 4 + 1] += av.y * kv.y;
                cv1[c * 4 + 2] += av.y * kv.z;
                cv1[c * 4 + 3] += av.y * kv.w;
            }
        }
    }

    // conv bias: add once per (f,n) -> only parity-0 waves
    if (p == 0) {
        #pragma unroll
        for (int n = 0; n < 16; ++n) {
            const float cb = conv_b[h * 16 + n];
            cv0[n] += cb;
            cv1[n] += cb;
        }
    }

    // ---- s = cv . wv ; a = sigmoid(s) ----
    float sp0 = 0.f, sp1 = 0.f;
    #pragma unroll
    for (int n = 0; n < 16; ++n) {
        const float wvn = sh_wv[h * 16 + n];       // broadcast read
        sp0 += cv0[n] * wvn;
        sp1 += cv1[n] * wvn;
    }
    red[(lane * 2 + 0) * 4 + wid] = sp0;
    red[(lane * 2 + 1) * 4 + wid] = sp1;
    __syncthreads();
    if (t < 128) {
        const float s = red[t * 4] + red[t * 4 + 1] + red[t * 4 + 2] + red[t * 4 + 3];
        sh_a[t] = 1.f / (1.f + expf(-s));
    }
    __syncthreads();

    // ---- d[n] = sum_f a[f] * cv[f][n] ----
    const float a0 = sh_a[lane * 2], a1 = sh_a[lane * 2 + 1];
    float dp[16];
    #pragma unroll
    for (int n = 0; n < 16; ++n) dp[n] = a0 * cv0[n] + a1 * cv1[n];
    #pragma unroll
    for (int off = 32; off > 0; off >>= 1) {
        #pragma unroll
        for (int n = 0; n < 16; ++n) dp[n] += __shfl_xor(dp[n], off);
    }
    if (lane == 0) {
        #pragma unroll
        for (int n = 0; n < 16; ++n) sh_dp[wid * 16 + n] = dp[n];
    }
    __syncthreads();
    if (t < 32) sh_d[t] = sh_dp[t] + sh_dp[t + 32];   // combine row parities
    __syncthreads();

    // ---- out0 = [qrow, d] @ W_out + b_out ----
    {
        const int m = t & 127, khalf = t >> 7;
        float acc = 0.f;
        const int kbase2 = khalf << 7;
        #pragma unroll 4
        for (int k = kbase2; k < kbase2 + 128; ++k)
            acc += qrow[k] * W_out[k * AA + m];
        if (khalf) {
            #pragma unroll
            for (int j = 0; j < 32; ++j)
                acc += sh_d[j] * W_out[(256 + j) * AA + m];
        } else {
            acc += b_out[m];
        }
        red[t] = acc;   // all prior red reads completed two barriers ago
    }
    __syncthreads();
    if (t < 128)
        out_attns[(size_t)b * AA + t] = red[t] + red[t + 128];
}

extern "C" void kernel_launch(void* const* d_in, const int* in_sizes, int n_in,
                              void* d_out, int out_size, void* d_ws, size_t ws_size,
                              hipStream_t stream) {
    const float* query       = (const float*)d_in[0];
    const float* attn_states = (const float*)d_in[1];
    const float* W_q         = (const float*)d_in[2];
    const float* conv_k      = (const float*)d_in[3];
    const float* conv_b      = (const float*)d_in[4];
    const float* W_out       = (const float*)d_in[5];
    const float* b_out       = (const float*)d_in[6];

    float* out_attns  = (float*)d_out;                         // B*A
    float* out_states = (float*)d_out + (size_t)BB * AA;       // B*(L-1)*A

    tpa_fused<<<BB, 256, 0, stream>>>(query, attn_states, W_q, conv_k, conv_b,
                                      W_out, b_out, out_attns, out_states);
}